// Round 6
// baseline (159.082 us; speedup 1.0000x reference)
//
#include <hip/hip_runtime.h>
#include <hip/hip_cooperative_groups.h>

namespace cg = cooperative_groups;

#define NN 17    // nodes
#define D  512   // feature dim
#define H  8     // heads
#define C1 515   // D + 3
#define M  256   // hidden

#define XPAD 20                              // [d][n] row stride (17 + pad)
#define RSN  36                              // reduction row: 32 outputs + pad
#define RSG  (NN * RSN)                      // 612 floats per group (2448 B, 16B-mult)
#define SMEM_FL (32 * RSG)                   // 19584 floats = 78.3 KB (union buffer)

__device__ __forceinline__ void fma4(float4& a, float x, const float4& w) {
    a.x = fmaf(x, w.x, a.x); a.y = fmaf(x, w.y, a.y);
    a.z = fmaf(x, w.z, a.z); a.w = fmaf(x, w.w, a.w);
}

// Single cooperative kernel, grid = 128 blocks x 256 threads.
// Phase A (all 128 blocks): f[h,n,e] = relu(Xs @ FC[h])     (FC read exactly once)
// Phase B (blocks 0..63):   hdn = tanh([f,ROI] @ W1 + b1)   (W1 read exactly once)
// Phase C (blocks 0..16):   scores -> softmax -> conv+relu+residual -> out
__global__ __launch_bounds__(256) void fused_all(
        const float* __restrict__ Xs, const float* __restrict__ ROIs,
        const float* __restrict__ FC, const float* __restrict__ W1,
        const float* __restrict__ b1, const float* __restrict__ W2,
        const float* __restrict__ b2, const float* __restrict__ conv_w,
        const float* __restrict__ conv_b, float* __restrict__ f,
        float* __restrict__ hdn, float* __restrict__ out) {
    cg::grid_group grid = cg::this_grid();
    __shared__ __align__(16) float sm[SMEM_FL];
    const int b = blockIdx.x, t = threadIdx.x;

    // ======== Phase A: k1 on all 128 blocks (et = b&15, h = b>>4) ========
    {
        const int et = b & 15, h = b >> 4;
        const int tw = t & 7, cgp = t >> 3;
        for (int i = t; i < NN * D; i += 256) {
            const int n = i >> 9, d = i & 511;
            sm[d * XPAD + n] = Xs[i];
        }
        __syncthreads();
        float4 acc[NN];
#pragma unroll
        for (int n = 0; n < NN; ++n) acc[n] = make_float4(0.f, 0.f, 0.f, 0.f);
        const float4* fc4 = (const float4*)(FC + (size_t)h * D * D) + et * 8 + tw;
#pragma unroll 4
        for (int i = 0; i < 16; ++i) {
            const int d = cgp + (i << 5);
            const float4 w = fc4[d << 7];        // [d][512/4] row stride 128
            const float* xr = sm + d * XPAD;
#pragma unroll
            for (int n4 = 0; n4 < 4; ++n4) {
                const float4 x = *(const float4*)(xr + (n4 << 2));
                fma4(acc[n4 * 4 + 0], x.x, w);
                fma4(acc[n4 * 4 + 1], x.y, w);
                fma4(acc[n4 * 4 + 2], x.z, w);
                fma4(acc[n4 * 4 + 3], x.w, w);
            }
            fma4(acc[16], xr[16], w);
        }
        __syncthreads();             // xs reads done; reuse sm for reduction
        float* rr = sm + cgp * RSG + tw * 4;
#pragma unroll
        for (int n = 0; n < NN; ++n) *(float4*)(rr + n * RSN) = acc[n];
        __syncthreads();
        for (int i = t; i < NN * 32; i += 256) {
            const int n = i >> 5, e = i & 31;
            float s = 0.f;
#pragma unroll 8
            for (int g = 0; g < 32; ++g) s += sm[g * RSG + n * RSN + e];
            f[((h * NN + n) << 9) + (et << 5) + e] = fmaxf(s, 0.f);
        }
    }
    grid.sync();

    // ======== Phase B: k2 on blocks 0..63 (mt = b&7, h = b>>3) ========
    if (b < 64) {
        const int mt = b & 7, h = b >> 3;
        const int tw = t & 7, cgp = t >> 3;
        for (int i = t; i < NN * D; i += 256) {
            const int n = i >> 9, d = i & 511;
            sm[d * XPAD + n] = f[((size_t)(h * NN) << 9) + i];
        }
        if (t < NN * 3) {
            const int n = t / 3, cc = t % 3;
            sm[(D + cc) * XPAD + n] = ROIs[t];
        }
        __syncthreads();
        float4 acc[NN];
#pragma unroll
        for (int n = 0; n < NN; ++n) acc[n] = make_float4(0.f, 0.f, 0.f, 0.f);
        const float4* w4 = (const float4*)(W1 + (size_t)h * C1 * M) + mt * 8 + tw;
#pragma unroll 4
        for (int i = 0; i < 16; ++i) {
            const int c = cgp + (i << 5);
            const float4 w = w4[c << 6];         // [c][256/4] row stride 64
            const float* xr = sm + c * XPAD;
#pragma unroll
            for (int n4 = 0; n4 < 4; ++n4) {
                const float4 x = *(const float4*)(xr + (n4 << 2));
                fma4(acc[n4 * 4 + 0], x.x, w);
                fma4(acc[n4 * 4 + 1], x.y, w);
                fma4(acc[n4 * 4 + 2], x.z, w);
                fma4(acc[n4 * 4 + 3], x.w, w);
            }
            fma4(acc[16], xr[16], w);
        }
        if (cgp < 3) {                           // tail rows c = 512..514 (ROI)
            const int c = D + cgp;
            const float4 w = w4[c << 6];
            const float* xr = sm + c * XPAD;
#pragma unroll
            for (int n4 = 0; n4 < 4; ++n4) {
                const float4 x = *(const float4*)(xr + (n4 << 2));
                fma4(acc[n4 * 4 + 0], x.x, w);
                fma4(acc[n4 * 4 + 1], x.y, w);
                fma4(acc[n4 * 4 + 2], x.z, w);
                fma4(acc[n4 * 4 + 3], x.w, w);
            }
            fma4(acc[16], xr[16], w);
        }
        __syncthreads();
        float* rr = sm + cgp * RSG + tw * 4;
#pragma unroll
        for (int n = 0; n < NN; ++n) *(float4*)(rr + n * RSN) = acc[n];
        __syncthreads();
        for (int i = t; i < NN * 32; i += 256) {
            const int n = i >> 5, m = i & 31;
            float s = b1[h * M + (mt << 5) + m];
#pragma unroll 8
            for (int g = 0; g < 32; ++g) s += sm[g * RSG + n * RSN + m];
            hdn[(h * NN + n) * M + (mt << 5) + m] = tanhf(s);
        }
    }
    grid.sync();

    // ======== Phase C: fused k3+k4 on blocks 0..16 (k = b) ========
    if (b < NN) {
        const int k = b;
        float* swk = sm;                       // [h][M+4], row 260 fl (1040 B, 16B-mult)
        float* sa  = sm + H * (M + 4);         // [h][NN]
        float* cw  = sa + H * NN;              // [H]
        for (int i = t; i < H * M; i += 256) {
            const int h = i >> 8, m = i & 255;
            swk[h * (M + 4) + m] = W2[(size_t)(h * M + m) * NN + k];
        }
        if (t < H) cw[t] = conv_w[t];
        __syncthreads();
        if (t < H * NN) {
            const int h = t / NN, n = t % NN;
            const float4* a4 = (const float4*)(hdn + (h * NN + n) * M);
            const float4* w4 = (const float4*)(swk + h * (M + 4));
            float acc = b2[h * NN + k];
#pragma unroll 8
            for (int m4 = 0; m4 < M / 4; ++m4) {
                const float4 av = a4[m4];
                const float4 wv = w4[m4];
                acc = fmaf(av.x, wv.x, acc); acc = fmaf(av.y, wv.y, acc);
                acc = fmaf(av.z, wv.z, acc); acc = fmaf(av.w, wv.w, acc);
            }
            sa[h * NN + n] = acc;
        }
        __syncthreads();
        if (t < H) {
            float mx = -1e30f;
#pragma unroll
            for (int n = 0; n < NN; ++n) mx = fmaxf(mx, sa[t * NN + n]);
            float e[NN];
            float s = 0.f;
#pragma unroll
            for (int n = 0; n < NN; ++n) { e[n] = __expf(sa[t * NN + n] - mx); s += e[n]; }
            const float inv = 1.f / s;
#pragma unroll
            for (int n = 0; n < NN; ++n) sa[t * NN + n] = e[n] * inv;
        }
        __syncthreads();
        const float cb = conv_b[0];
        float acc0 = 0.f, acc1 = 0.f;
        for (int h = 0; h < H; ++h) {
            float w0 = 0.f, w1 = 0.f;
#pragma unroll
            for (int n = 0; n < NN; ++n) {
                const float a = sa[h * NN + n];
                const float* fr = f + (size_t)((h * NN + n) << 9);
                w0 = fmaf(a, fr[t], w0);
                w1 = fmaf(a, fr[t + 256], w1);
            }
            acc0 = fmaf(cw[h], w0, acc0);
            acc1 = fmaf(cw[h], w1, acc1);
        }
        out[(k << 9) + t]       = fmaxf(acc0 + cb, 0.f) + Xs[(k << 9) + t];
        out[(k << 9) + t + 256] = fmaxf(acc1 + cb, 0.f) + Xs[(k << 9) + t + 256];
        if (k == 0 && t < NN * 3) out[NN * D + t] = ROIs[t];
    }
}

extern "C" void kernel_launch(void* const* d_in, const int* in_sizes, int n_in,
                              void* d_out, int out_size, void* d_ws, size_t ws_size,
                              hipStream_t stream) {
    const float* Xs     = (const float*)d_in[0];
    const float* ROIs   = (const float*)d_in[1];
    // d_in[2] = adj, unused
    const float* FC     = (const float*)d_in[3];
    const float* W1     = (const float*)d_in[4];
    const float* b1     = (const float*)d_in[5];
    const float* W2     = (const float*)d_in[6];
    const float* b2     = (const float*)d_in[7];
    const float* conv_w = (const float*)d_in[8];
    const float* conv_b = (const float*)d_in[9];
    float* out = (float*)d_out;

    float* f   = (float*)d_ws;                 // H*NN*D  = 69632 floats
    float* hdn = f + H * NN * D;               // H*NN*M  = 34816 floats

    void* args[] = {(void*)&Xs, (void*)&ROIs, (void*)&FC, (void*)&W1, (void*)&b1,
                    (void*)&W2, (void*)&b2, (void*)&conv_w, (void*)&conv_b,
                    (void*)&f, (void*)&hdn, (void*)&out};
    hipLaunchCooperativeKernel(reinterpret_cast<void*>(&fused_all),
                               dim3(128), dim3(256), args, 0, stream);
}

// Round 7
// 116.820 us; speedup vs baseline: 1.3618x; 1.3618x over previous
//
#include <hip/hip_runtime.h>

#define NN 17    // nodes
#define D  512   // feature dim
#define H  8     // heads
#define C1 515   // D + 3
#define M  256   // hidden

#define XPAD 20                              // [d][n] row stride (17 + pad)
#define RSN  36                              // reduction row: 32 outputs + pad
#define RSG  (NN * RSN)                      // 612 floats per group (2448 B, 16B-mult)
#define SMEM_FL (32 * RSG)                   // 19584 floats = 78.3 KB (union buffer)

#define MAGIC 0x13579BDFu

__device__ __forceinline__ void fma4(float4& a, float x, const float4& w) {
    a.x = fmaf(x, w.x, a.x); a.y = fmaf(x, w.y, a.y);
    a.z = fmaf(x, w.z, a.z); a.w = fmaf(x, w.w, a.w);
}

// sync buffer layout (unsigned words, each counter on its own 128B line):
//   s[h*32]  : ctr1[h], h=0..7  (phase-A arrivals per head, target 16)
//   s[256]   : ctr2             (phase-B arrivals, target 64)
//   s[288]   : init flag (MAGIC when counters are zeroed)
__device__ __forceinline__ void sync_arrive(unsigned* s, unsigned* ctr) {
    while (__hip_atomic_load(&s[288], __ATOMIC_ACQUIRE, __HIP_MEMORY_SCOPE_AGENT) != MAGIC)
        __builtin_amdgcn_s_sleep(1);
    __threadfence();   // release: make this block's global writes visible device-wide
    __hip_atomic_fetch_add(ctr, 1u, __ATOMIC_RELEASE, __HIP_MEMORY_SCOPE_AGENT);
}

__device__ __forceinline__ void sync_wait(unsigned* ctr, unsigned target) {
    while (__hip_atomic_load(ctr, __ATOMIC_ACQUIRE, __HIP_MEMORY_SCOPE_AGENT) < target)
        __builtin_amdgcn_s_sleep(1);
    __threadfence();   // acquire: invalidate stale cached lines before reading
}

// Single kernel, plain launch, grid = 128 blocks x 256 threads (2 blocks/CU
// at 78.3 KB LDS -> capacity 512 >> 128, all blocks co-resident).
// Phase A (all 128 blocks): f[h,n,e] = relu(Xs @ FC[h])     (FC read once)
// Phase B (blocks 0..63):   hdn = tanh([f,ROI] @ W1 + b1)   (W1 read once)
// Phase C (blocks 0..16):   scores -> softmax -> conv+relu+residual -> out
__global__ __launch_bounds__(256) void fused_all(
        const float* __restrict__ Xs, const float* __restrict__ ROIs,
        const float* __restrict__ FC, const float* __restrict__ W1,
        const float* __restrict__ b1, const float* __restrict__ W2,
        const float* __restrict__ b2, const float* __restrict__ conv_w,
        const float* __restrict__ conv_b, float* __restrict__ f,
        float* __restrict__ hdn, unsigned* __restrict__ sy,
        float* __restrict__ out) {
    __shared__ __align__(16) float sm[SMEM_FL];
    const int b = blockIdx.x, t = threadIdx.x;

    if (b == 0 && t == 0) {   // init sync counters behind the flag
        for (int h = 0; h < H; ++h)
            __hip_atomic_store(&sy[h * 32], 0u, __ATOMIC_RELAXED, __HIP_MEMORY_SCOPE_AGENT);
        __hip_atomic_store(&sy[256], 0u, __ATOMIC_RELAXED, __HIP_MEMORY_SCOPE_AGENT);
        __threadfence();
        __hip_atomic_store(&sy[288], MAGIC, __ATOMIC_RELEASE, __HIP_MEMORY_SCOPE_AGENT);
    }

    // ======== Phase A: all 128 blocks (et = b&15, h = b>>4) ========
    {
        const int et = b & 15, h = b >> 4;
        const int tw = t & 7, cgp = t >> 3;
        for (int i = t; i < NN * D; i += 256) {
            const int n = i >> 9, d = i & 511;
            sm[d * XPAD + n] = Xs[i];
        }
        __syncthreads();
        float4 acc[NN];
#pragma unroll
        for (int n = 0; n < NN; ++n) acc[n] = make_float4(0.f, 0.f, 0.f, 0.f);
        const float4* fc4 = (const float4*)(FC + (size_t)h * D * D) + et * 8 + tw;
#pragma unroll 4
        for (int i = 0; i < 16; ++i) {
            const int d = cgp + (i << 5);
            const float4 w = fc4[d << 7];        // [d][512/4] row stride 128
            const float* xr = sm + d * XPAD;
#pragma unroll
            for (int n4 = 0; n4 < 4; ++n4) {
                const float4 x = *(const float4*)(xr + (n4 << 2));
                fma4(acc[n4 * 4 + 0], x.x, w);
                fma4(acc[n4 * 4 + 1], x.y, w);
                fma4(acc[n4 * 4 + 2], x.z, w);
                fma4(acc[n4 * 4 + 3], x.w, w);
            }
            fma4(acc[16], xr[16], w);
        }
        __syncthreads();             // xs reads done; reuse sm for reduction
        float* rr = sm + cgp * RSG + tw * 4;
#pragma unroll
        for (int n = 0; n < NN; ++n) *(float4*)(rr + n * RSN) = acc[n];
        __syncthreads();
        for (int i = t; i < NN * 32; i += 256) {
            const int n = i >> 5, e = i & 31;
            float s = 0.f;
#pragma unroll 8
            for (int g = 0; g < 32; ++g) s += sm[g * RSG + n * RSN + e];
            f[((h * NN + n) << 9) + (et << 5) + e] = fmaxf(s, 0.f);
        }
    }
    __syncthreads();                              // drain f stores (vmcnt)
    if (t == 0) sync_arrive(sy, &sy[(b >> 4) * 32]);
    if (b >= 64) return;                          // not needed further
    if (t == 0) sync_wait(&sy[(b >> 3) * 32], 16u);
    __syncthreads();

    // ======== Phase B: blocks 0..63 (mt = b&7, h = b>>3) ========
    {
        const int mt = b & 7, h = b >> 3;
        const int tw = t & 7, cgp = t >> 3;
        for (int i = t; i < NN * D; i += 256) {
            const int n = i >> 9, d = i & 511;
            sm[d * XPAD + n] = f[((size_t)(h * NN) << 9) + i];
        }
        if (t < NN * 3) {
            const int n = t / 3, cc = t % 3;
            sm[(D + cc) * XPAD + n] = ROIs[t];
        }
        __syncthreads();
        float4 acc[NN];
#pragma unroll
        for (int n = 0; n < NN; ++n) acc[n] = make_float4(0.f, 0.f, 0.f, 0.f);
        const float4* w4 = (const float4*)(W1 + (size_t)h * C1 * M) + mt * 8 + tw;
#pragma unroll 4
        for (int i = 0; i < 16; ++i) {
            const int c = cgp + (i << 5);
            const float4 w = w4[c << 6];         // [c][256/4] row stride 64
            const float* xr = sm + c * XPAD;
#pragma unroll
            for (int n4 = 0; n4 < 4; ++n4) {
                const float4 x = *(const float4*)(xr + (n4 << 2));
                fma4(acc[n4 * 4 + 0], x.x, w);
                fma4(acc[n4 * 4 + 1], x.y, w);
                fma4(acc[n4 * 4 + 2], x.z, w);
                fma4(acc[n4 * 4 + 3], x.w, w);
            }
            fma4(acc[16], xr[16], w);
        }
        if (cgp < 3) {                           // tail rows c = 512..514 (ROI)
            const int c = D + cgp;
            const float4 w = w4[c << 6];
            const float* xr = sm + c * XPAD;
#pragma unroll
            for (int n4 = 0; n4 < 4; ++n4) {
                const float4 x = *(const float4*)(xr + (n4 << 2));
                fma4(acc[n4 * 4 + 0], x.x, w);
                fma4(acc[n4 * 4 + 1], x.y, w);
                fma4(acc[n4 * 4 + 2], x.z, w);
                fma4(acc[n4 * 4 + 3], x.w, w);
            }
            fma4(acc[16], xr[16], w);
        }
        __syncthreads();
        float* rr = sm + cgp * RSG + tw * 4;
#pragma unroll
        for (int n = 0; n < NN; ++n) *(float4*)(rr + n * RSN) = acc[n];
        __syncthreads();
        for (int i = t; i < NN * 32; i += 256) {
            const int n = i >> 5, m = i & 31;
            float s = b1[h * M + (mt << 5) + m];
#pragma unroll 8
            for (int g = 0; g < 32; ++g) s += sm[g * RSG + n * RSN + m];
            hdn[(h * NN + n) * M + (mt << 5) + m] = tanhf(s);
        }
    }
    __syncthreads();                              // drain hdn stores
    if (t == 0) sync_arrive(sy, &sy[256]);
    if (b >= NN) return;
    if (t == 0) sync_wait(&sy[256], 64u);
    __syncthreads();

    // ======== Phase C: blocks 0..16 (k = b) ========
    {
        const int k = b;
        float* swk = sm;                       // [h][M+4], row 260 fl (16B-mult)
        float* sa  = sm + H * (M + 4);         // [h][NN]
        float* cw  = sa + H * NN;              // [H]
        for (int i = t; i < H * M; i += 256) {
            const int h = i >> 8, m = i & 255;
            swk[h * (M + 4) + m] = W2[(size_t)(h * M + m) * NN + k];
        }
        if (t < H) cw[t] = conv_w[t];
        __syncthreads();
        if (t < H * NN) {
            const int h = t / NN, n = t % NN;
            const float4* a4 = (const float4*)(hdn + (h * NN + n) * M);
            const float4* w4 = (const float4*)(swk + h * (M + 4));
            float acc = b2[h * NN + k];
#pragma unroll 8
            for (int m4 = 0; m4 < M / 4; ++m4) {
                const float4 av = a4[m4];
                const float4 wv = w4[m4];
                acc = fmaf(av.x, wv.x, acc); acc = fmaf(av.y, wv.y, acc);
                acc = fmaf(av.z, wv.z, acc); acc = fmaf(av.w, wv.w, acc);
            }
            sa[h * NN + n] = acc;
        }
        __syncthreads();
        if (t < H) {
            float mx = -1e30f;
#pragma unroll
            for (int n = 0; n < NN; ++n) mx = fmaxf(mx, sa[t * NN + n]);
            float e[NN];
            float s = 0.f;
#pragma unroll
            for (int n = 0; n < NN; ++n) { e[n] = __expf(sa[t * NN + n] - mx); s += e[n]; }
            const float inv = 1.f / s;
#pragma unroll
            for (int n = 0; n < NN; ++n) sa[t * NN + n] = e[n] * inv;
        }
        __syncthreads();
        const float cb = conv_b[0];
        float acc0 = 0.f, acc1 = 0.f;
        for (int h = 0; h < H; ++h) {
            float w0 = 0.f, w1 = 0.f;
#pragma unroll
            for (int n = 0; n < NN; ++n) {
                const float a = sa[h * NN + n];
                const float* fr = f + (size_t)((h * NN + n) << 9);
                w0 = fmaf(a, fr[t], w0);
                w1 = fmaf(a, fr[t + 256], w1);
            }
            acc0 = fmaf(cw[h], w0, acc0);
            acc1 = fmaf(cw[h], w1, acc1);
        }
        out[(k << 9) + t]       = fmaxf(acc0 + cb, 0.f) + Xs[(k << 9) + t];
        out[(k << 9) + t + 256] = fmaxf(acc1 + cb, 0.f) + Xs[(k << 9) + t + 256];
        if (k == 0 && t < NN * 3) out[NN * D + t] = ROIs[t];
    }
}

extern "C" void kernel_launch(void* const* d_in, const int* in_sizes, int n_in,
                              void* d_out, int out_size, void* d_ws, size_t ws_size,
                              hipStream_t stream) {
    const float* Xs     = (const float*)d_in[0];
    const float* ROIs   = (const float*)d_in[1];
    // d_in[2] = adj, unused
    const float* FC     = (const float*)d_in[3];
    const float* W1     = (const float*)d_in[4];
    const float* b1     = (const float*)d_in[5];
    const float* W2     = (const float*)d_in[6];
    const float* b2     = (const float*)d_in[7];
    const float* conv_w = (const float*)d_in[8];
    const float* conv_b = (const float*)d_in[9];
    float* out = (float*)d_out;

    float* f      = (float*)d_ws;              // H*NN*D  = 69632 floats
    float* hdn    = f + H * NN * D;            // H*NN*M  = 34816 floats
    unsigned* sy  = (unsigned*)(hdn + H * NN * M);   // 512 words sync area

    fused_all<<<128, 256, 0, stream>>>(Xs, ROIs, FC, W1, b1, W2, b2,
                                       conv_w, conv_b, f, hdn, sy, out);
}

// Round 8
// 112.161 us; speedup vs baseline: 1.4183x; 1.0415x over previous
//
#include <hip/hip_runtime.h>

#define NN 17    // nodes
#define D  512   // feature dim
#define H  8     // heads
#define C1 515   // D + 3
#define M  256   // hidden

#define XPAD 20                              // [d][n] row stride (17 + pad)
#define RSN  36                              // reduction row: 32 outputs + pad
#define RSG  (NN * RSN)                      // 612 floats per group (2448 B, 16B-mult)
#define SMEM_FL (32 * RSG)                   // 19584 floats = 78.3 KB (union buffer)

#define MAGIC 0x13579BDFu

__device__ __forceinline__ void fma4(float4& a, float x, const float4& w) {
    a.x = fmaf(x, w.x, a.x); a.y = fmaf(x, w.y, a.y);
    a.z = fmaf(x, w.z, a.z); a.w = fmaf(x, w.w, a.w);
}

// sync buffer layout (unsigned words, each counter on its own 128B line):
//   s[h*32]  : ctr1[h], h=0..7  (phase-A arrivals per head, target 16)
//   s[256]   : ctr2             (phase-B arrivals, target 64)
//   s[288]   : init flag (MAGIC when counters are zeroed)
// Fence hygiene (round-7 lesson): exactly ONE wbl2 per arrival (the RELEASE
// fetch_add), RELAXED spins (no per-poll buffer_inv), ONE acquire fence after
// each successful wait.
__device__ __forceinline__ void sync_arrive(unsigned* s, unsigned* ctr) {
    while (__hip_atomic_load(&s[288], __ATOMIC_RELAXED, __HIP_MEMORY_SCOPE_AGENT) != MAGIC)
        __builtin_amdgcn_s_sleep(1);
    __builtin_amdgcn_fence(__ATOMIC_ACQUIRE, "agent");   // flag -> counters zeroed
    __hip_atomic_fetch_add(ctr, 1u, __ATOMIC_RELEASE, __HIP_MEMORY_SCOPE_AGENT);
}

__device__ __forceinline__ void sync_wait(unsigned* ctr, unsigned target) {
    while (__hip_atomic_load(ctr, __ATOMIC_RELAXED, __HIP_MEMORY_SCOPE_AGENT) < target)
        __builtin_amdgcn_s_sleep(1);
    __builtin_amdgcn_fence(__ATOMIC_ACQUIRE, "agent");   // see producers' writes
}

// Single kernel, plain launch, grid = 128 blocks x 256 threads (2 blocks/CU
// at 78.3 KB LDS -> capacity 512 >> 128, all blocks co-resident).
// Phase A (all 128 blocks): f[h,n,e] = relu(Xs @ FC[h])     (FC read once)
// Phase B (blocks 0..63):   hdn = tanh([f,ROI] @ W1 + b1)   (W1 read once)
// Phase C (blocks 0..16):   scores -> softmax -> conv+relu+residual -> out
__global__ __launch_bounds__(256) void fused_all(
        const float* __restrict__ Xs, const float* __restrict__ ROIs,
        const float* __restrict__ FC, const float* __restrict__ W1,
        const float* __restrict__ b1, const float* __restrict__ W2,
        const float* __restrict__ b2, const float* __restrict__ conv_w,
        const float* __restrict__ conv_b, float* __restrict__ f,
        float* __restrict__ hdn, unsigned* __restrict__ sy,
        float* __restrict__ out) {
    __shared__ __align__(16) float sm[SMEM_FL];
    const int b = blockIdx.x, t = threadIdx.x;

    if (b == 0 && t == 0) {   // init sync counters behind the flag
        for (int h = 0; h < H; ++h)
            __hip_atomic_store(&sy[h * 32], 0u, __ATOMIC_RELAXED, __HIP_MEMORY_SCOPE_AGENT);
        __hip_atomic_store(&sy[256], 0u, __ATOMIC_RELAXED, __HIP_MEMORY_SCOPE_AGENT);
        __hip_atomic_store(&sy[288], MAGIC, __ATOMIC_RELEASE, __HIP_MEMORY_SCOPE_AGENT);
    }

    // ======== Phase A: all 128 blocks (et = b&15, h = b>>4) ========
    {
        const int et = b & 15, h = b >> 4;
        const int tw = t & 7, cgp = t >> 3;
        for (int i = t; i < NN * D; i += 256) {
            const int n = i >> 9, d = i & 511;
            sm[d * XPAD + n] = Xs[i];
        }
        __syncthreads();
        float4 acc[NN];
#pragma unroll
        for (int n = 0; n < NN; ++n) acc[n] = make_float4(0.f, 0.f, 0.f, 0.f);
        const float4* fc4 = (const float4*)(FC + (size_t)h * D * D) + et * 8 + tw;
#pragma unroll 4
        for (int i = 0; i < 16; ++i) {
            const int d = cgp + (i << 5);
            const float4 w = fc4[d << 7];        // [d][512/4] row stride 128
            const float* xr = sm + d * XPAD;
#pragma unroll
            for (int n4 = 0; n4 < 4; ++n4) {
                const float4 x = *(const float4*)(xr + (n4 << 2));
                fma4(acc[n4 * 4 + 0], x.x, w);
                fma4(acc[n4 * 4 + 1], x.y, w);
                fma4(acc[n4 * 4 + 2], x.z, w);
                fma4(acc[n4 * 4 + 3], x.w, w);
            }
            fma4(acc[16], xr[16], w);
        }
        __syncthreads();             // xs reads done; reuse sm for reduction
        float* rr = sm + cgp * RSG + tw * 4;
#pragma unroll
        for (int n = 0; n < NN; ++n) *(float4*)(rr + n * RSN) = acc[n];
        __syncthreads();
        for (int i = t; i < NN * 32; i += 256) {
            const int n = i >> 5, e = i & 31;
            float s = 0.f;
#pragma unroll 8
            for (int g = 0; g < 32; ++g) s += sm[g * RSG + n * RSN + e];
            f[((h * NN + n) << 9) + (et << 5) + e] = fmaxf(s, 0.f);
        }
    }
    __syncthreads();                              // all waves' f stores issued
    if (t == 0) sync_arrive(sy, &sy[(b >> 4) * 32]);
    if (b >= 64) return;                          // not needed further
    if (t == 0) sync_wait(&sy[(b >> 3) * 32], 16u);
    __syncthreads();

    // ======== Phase B: blocks 0..63 (mt = b&7, h = b>>3) ========
    {
        const int mt = b & 7, h = b >> 3;
        const int tw = t & 7, cgp = t >> 3;
        for (int i = t; i < NN * D; i += 256) {
            const int n = i >> 9, d = i & 511;
            sm[d * XPAD + n] = f[((size_t)(h * NN) << 9) + i];
        }
        if (t < NN * 3) {
            const int n = t / 3, cc = t % 3;
            sm[(D + cc) * XPAD + n] = ROIs[t];
        }
        __syncthreads();
        float4 acc[NN];
#pragma unroll
        for (int n = 0; n < NN; ++n) acc[n] = make_float4(0.f, 0.f, 0.f, 0.f);
        const float4* w4 = (const float4*)(W1 + (size_t)h * C1 * M) + mt * 8 + tw;
#pragma unroll 4
        for (int i = 0; i < 16; ++i) {
            const int c = cgp + (i << 5);
            const float4 w = w4[c << 6];         // [c][256/4] row stride 64
            const float* xr = sm + c * XPAD;
#pragma unroll
            for (int n4 = 0; n4 < 4; ++n4) {
                const float4 x = *(const float4*)(xr + (n4 << 2));
                fma4(acc[n4 * 4 + 0], x.x, w);
                fma4(acc[n4 * 4 + 1], x.y, w);
                fma4(acc[n4 * 4 + 2], x.z, w);
                fma4(acc[n4 * 4 + 3], x.w, w);
            }
            fma4(acc[16], xr[16], w);
        }
        if (cgp < 3) {                           // tail rows c = 512..514 (ROI)
            const int c = D + cgp;
            const float4 w = w4[c << 6];
            const float* xr = sm + c * XPAD;
#pragma unroll
            for (int n4 = 0; n4 < 4; ++n4) {
                const float4 x = *(const float4*)(xr + (n4 << 2));
                fma4(acc[n4 * 4 + 0], x.x, w);
                fma4(acc[n4 * 4 + 1], x.y, w);
                fma4(acc[n4 * 4 + 2], x.z, w);
                fma4(acc[n4 * 4 + 3], x.w, w);
            }
            fma4(acc[16], xr[16], w);
        }
        __syncthreads();
        float* rr = sm + cgp * RSG + tw * 4;
#pragma unroll
        for (int n = 0; n < NN; ++n) *(float4*)(rr + n * RSN) = acc[n];
        __syncthreads();
        for (int i = t; i < NN * 32; i += 256) {
            const int n = i >> 5, m = i & 31;
            float s = b1[h * M + (mt << 5) + m];
#pragma unroll 8
            for (int g = 0; g < 32; ++g) s += sm[g * RSG + n * RSN + m];
            hdn[(h * NN + n) * M + (mt << 5) + m] = tanhf(s);
        }
    }
    __syncthreads();                              // all waves' hdn stores issued
    if (t == 0) sync_arrive(sy, &sy[256]);
    if (b >= NN) return;
    if (t == 0) sync_wait(&sy[256], 64u);
    __syncthreads();

    // ======== Phase C: blocks 0..16 (k = b) ========
    {
        const int k = b;
        float* swk = sm;                       // [h][M+4], row 260 fl (16B-mult)
        float* sa  = sm + H * (M + 4);         // [h][NN]
        float* cw  = sa + H * NN;              // [H]
        for (int i = t; i < H * M; i += 256) {
            const int h = i >> 8, m = i & 255;
            swk[h * (M + 4) + m] = W2[(size_t)(h * M + m) * NN + k];
        }
        if (t < H) cw[t] = conv_w[t];
        __syncthreads();
        if (t < H * NN) {
            const int h = t / NN, n = t % NN;
            const float4* a4 = (const float4*)(hdn + (h * NN + n) * M);
            const float4* w4 = (const float4*)(swk + h * (M + 4));
            float acc = b2[h * NN + k];
#pragma unroll 8
            for (int m4 = 0; m4 < M / 4; ++m4) {
                const float4 av = a4[m4];
                const float4 wv = w4[m4];
                acc = fmaf(av.x, wv.x, acc); acc = fmaf(av.y, wv.y, acc);
                acc = fmaf(av.z, wv.z, acc); acc = fmaf(av.w, wv.w, acc);
            }
            sa[h * NN + n] = acc;
        }
        __syncthreads();
        if (t < H) {
            float mx = -1e30f;
#pragma unroll
            for (int n = 0; n < NN; ++n) mx = fmaxf(mx, sa[t * NN + n]);
            float e[NN];
            float s = 0.f;
#pragma unroll
            for (int n = 0; n < NN; ++n) { e[n] = __expf(sa[t * NN + n] - mx); s += e[n]; }
            const float inv = 1.f / s;
#pragma unroll
            for (int n = 0; n < NN; ++n) sa[t * NN + n] = e[n] * inv;
        }
        __syncthreads();
        const float cb = conv_b[0];
        float acc0 = 0.f, acc1 = 0.f;
        for (int h = 0; h < H; ++h) {
            float w0 = 0.f, w1 = 0.f;
#pragma unroll
            for (int n = 0; n < NN; ++n) {
                const float a = sa[h * NN + n];
                const float* fr = f + (size_t)((h * NN + n) << 9);
                w0 = fmaf(a, fr[t], w0);
                w1 = fmaf(a, fr[t + 256], w1);
            }
            acc0 = fmaf(cw[h], w0, acc0);
            acc1 = fmaf(cw[h], w1, acc1);
        }
        out[(k << 9) + t]       = fmaxf(acc0 + cb, 0.f) + Xs[(k << 9) + t];
        out[(k << 9) + t + 256] = fmaxf(acc1 + cb, 0.f) + Xs[(k << 9) + t + 256];
        if (k == 0 && t < NN * 3) out[NN * D + t] = ROIs[t];
    }
}

extern "C" void kernel_launch(void* const* d_in, const int* in_sizes, int n_in,
                              void* d_out, int out_size, void* d_ws, size_t ws_size,
                              hipStream_t stream) {
    const float* Xs     = (const float*)d_in[0];
    const float* ROIs   = (const float*)d_in[1];
    // d_in[2] = adj, unused
    const float* FC     = (const float*)d_in[3];
    const float* W1     = (const float*)d_in[4];
    const float* b1     = (const float*)d_in[5];
    const float* W2     = (const float*)d_in[6];
    const float* b2     = (const float*)d_in[7];
    const float* conv_w = (const float*)d_in[8];
    const float* conv_b = (const float*)d_in[9];
    float* out = (float*)d_out;

    float* f      = (float*)d_ws;              // H*NN*D  = 69632 floats
    float* hdn    = f + H * NN * D;            // H*NN*M  = 34816 floats
    unsigned* sy  = (unsigned*)(hdn + H * NN * M);   // 512 words sync area

    fused_all<<<128, 256, 0, stream>>>(Xs, ROIs, FC, W1, b1, W2, b2,
                                       conv_w, conv_b, f, hdn, sy, out);
}

// Round 9
// 108.957 us; speedup vs baseline: 1.4600x; 1.0294x over previous
//
#include <hip/hip_runtime.h>

#define NN 17    // nodes
#define D  512   // feature dim
#define H  8     // heads
#define C1 515   // D + 3
#define M  256   // hidden

#define XPAD 20                              // [d][n] row stride (17 + pad)
#define RSN  36                              // reduction row: 32 outputs + pad
#define RSG  (NN * RSN)                      // 612 floats per group (2448 B, 16B-mult)
#define SMEM_FL (32 * RSG)                   // 19584 floats = 78.3 KB (union buffer)

__device__ __forceinline__ void fma4(float4& a, float x, const float4& w) {
    a.x = fmaf(x, w.x, a.x); a.y = fmaf(x, w.y, a.y);
    a.z = fmaf(x, w.z, a.z); a.w = fmaf(x, w.w, a.w);
}

// ===== Kernel A: f[h,n,e] = relu(Xs @ FC[h]); FC read exactly once. =====
// grid = 128 (et = b&15 e-tile of 32, h = b>>4), block = 256.
// Also zeroes the sync counter for kernel B (kernel boundary publishes it).
__global__ __launch_bounds__(256) void ka(const float* __restrict__ Xs,
                                          const float* __restrict__ FC,
                                          float* __restrict__ f,
                                          unsigned* __restrict__ sy) {
    const int b = blockIdx.x, t = threadIdx.x;
    if (b == 0 && t == 0)
        __hip_atomic_store(&sy[0], 0u, __ATOMIC_RELAXED, __HIP_MEMORY_SCOPE_AGENT);
    __shared__ __align__(16) float sm[SMEM_FL];
    const int et = b & 15, h = b >> 4;
    const int tw = t & 7, cgp = t >> 3;
    for (int i = t; i < NN * D; i += 256) {
        const int n = i >> 9, d = i & 511;
        sm[d * XPAD + n] = Xs[i];
    }
    __syncthreads();
    float4 acc[NN];
#pragma unroll
    for (int n = 0; n < NN; ++n) acc[n] = make_float4(0.f, 0.f, 0.f, 0.f);
    const float4* fc4 = (const float4*)(FC + (size_t)h * D * D) + et * 8 + tw;
#pragma unroll 4
    for (int i = 0; i < 16; ++i) {
        const int d = cgp + (i << 5);
        const float4 w = fc4[d << 7];            // [d][512/4] row stride 128
        const float* xr = sm + d * XPAD;
#pragma unroll
        for (int n4 = 0; n4 < 4; ++n4) {
            const float4 x = *(const float4*)(xr + (n4 << 2));
            fma4(acc[n4 * 4 + 0], x.x, w);
            fma4(acc[n4 * 4 + 1], x.y, w);
            fma4(acc[n4 * 4 + 2], x.z, w);
            fma4(acc[n4 * 4 + 3], x.w, w);
        }
        fma4(acc[16], xr[16], w);
    }
    __syncthreads();                 // xs reads done; reuse sm for reduction
    float* rr = sm + cgp * RSG + tw * 4;
#pragma unroll
    for (int n = 0; n < NN; ++n) *(float4*)(rr + n * RSN) = acc[n];
    __syncthreads();
    for (int i = t; i < NN * 32; i += 256) {
        const int n = i >> 5, e = i & 31;
        float s = 0.f;
#pragma unroll 8
        for (int g = 0; g < 32; ++g) s += sm[g * RSG + n * RSN + e];
        f[((h * NN + n) << 9) + (et << 5) + e] = fmaxf(s, 0.f);
    }
}

// ===== Kernel B+C =====
// Phase B (all 64 blocks): hdn = tanh([f,ROI] @ W1 + b1)  (W1 read once)
// barrier: 64 RELEASE arrivals -> blocks 0..16 relaxed-spin + acquire fence
// Phase C (blocks 0..16): scores -> softmax -> conv+relu+residual -> out
__global__ __launch_bounds__(256) void kbc(
        const float* __restrict__ Xs, const float* __restrict__ ROIs,
        const float* __restrict__ W1, const float* __restrict__ b1,
        const float* __restrict__ W2, const float* __restrict__ b2,
        const float* __restrict__ conv_w, const float* __restrict__ conv_b,
        const float* __restrict__ f, float* __restrict__ hdn,
        unsigned* __restrict__ sy, float* __restrict__ out) {
    __shared__ __align__(16) float sm[SMEM_FL];
    const int b = blockIdx.x, t = threadIdx.x;

    // ======== Phase B (mt = b&7, h = b>>3) ========
    {
        const int mt = b & 7, h = b >> 3;
        const int tw = t & 7, cgp = t >> 3;
        for (int i = t; i < NN * D; i += 256) {
            const int n = i >> 9, d = i & 511;
            sm[d * XPAD + n] = f[((size_t)(h * NN) << 9) + i];
        }
        if (t < NN * 3) {
            const int n = t / 3, cc = t % 3;
            sm[(D + cc) * XPAD + n] = ROIs[t];
        }
        __syncthreads();
        float4 acc[NN];
#pragma unroll
        for (int n = 0; n < NN; ++n) acc[n] = make_float4(0.f, 0.f, 0.f, 0.f);
        const float4* w4 = (const float4*)(W1 + (size_t)h * C1 * M) + mt * 8 + tw;
#pragma unroll 4
        for (int i = 0; i < 16; ++i) {
            const int c = cgp + (i << 5);
            const float4 w = w4[c << 6];         // [c][256/4] row stride 64
            const float* xr = sm + c * XPAD;
#pragma unroll
            for (int n4 = 0; n4 < 4; ++n4) {
                const float4 x = *(const float4*)(xr + (n4 << 2));
                fma4(acc[n4 * 4 + 0], x.x, w);
                fma4(acc[n4 * 4 + 1], x.y, w);
                fma4(acc[n4 * 4 + 2], x.z, w);
                fma4(acc[n4 * 4 + 3], x.w, w);
            }
            fma4(acc[16], xr[16], w);
        }
        if (cgp < 3) {                           // tail rows c = 512..514 (ROI)
            const int c = D + cgp;
            const float4 w = w4[c << 6];
            const float* xr = sm + c * XPAD;
#pragma unroll
            for (int n4 = 0; n4 < 4; ++n4) {
                const float4 x = *(const float4*)(xr + (n4 << 2));
                fma4(acc[n4 * 4 + 0], x.x, w);
                fma4(acc[n4 * 4 + 1], x.y, w);
                fma4(acc[n4 * 4 + 2], x.z, w);
                fma4(acc[n4 * 4 + 3], x.w, w);
            }
            fma4(acc[16], xr[16], w);
        }
        __syncthreads();
        float* rr = sm + cgp * RSG + tw * 4;
#pragma unroll
        for (int n = 0; n < NN; ++n) *(float4*)(rr + n * RSN) = acc[n];
        __syncthreads();
        for (int i = t; i < NN * 32; i += 256) {
            const int n = i >> 5, m = i & 31;
            float s = b1[h * M + (mt << 5) + m];
#pragma unroll 8
            for (int g = 0; g < 32; ++g) s += sm[g * RSG + n * RSN + m];
            hdn[(h * NN + n) * M + (mt << 5) + m] = tanhf(s);
        }
    }
    __syncthreads();      // each wave drains its hdn stores (vmcnt 0) at barrier
    if (t == 0)           // one RELEASE add: single L2 writeback per block
        __hip_atomic_fetch_add(&sy[0], 1u, __ATOMIC_RELEASE, __HIP_MEMORY_SCOPE_AGENT);
    if (b >= NN) return;
    if (t == 0) {
        while (__hip_atomic_load(&sy[0], __ATOMIC_RELAXED, __HIP_MEMORY_SCOPE_AGENT) < 64u)
            __builtin_amdgcn_s_sleep(1);
        __builtin_amdgcn_fence(__ATOMIC_ACQUIRE, "agent");   // one buffer_inv
    }
    __syncthreads();

    // ======== Phase C (k = b) ========
    {
        const int k = b;
        float* swk = sm;                       // [h][M+4], row 260 fl (16B-mult)
        float* sa  = sm + H * (M + 4);         // [h][NN]
        float* cw  = sa + H * NN;              // [H]
        for (int i = t; i < H * M; i += 256) {
            const int h = i >> 8, m = i & 255;
            swk[h * (M + 4) + m] = W2[(size_t)(h * M + m) * NN + k];
        }
        if (t < H) cw[t] = conv_w[t];
        __syncthreads();
        if (t < H * NN) {
            const int h = t / NN, n = t % NN;
            const float4* a4 = (const float4*)(hdn + (h * NN + n) * M);
            const float4* w4 = (const float4*)(swk + h * (M + 4));
            float acc = b2[h * NN + k];
#pragma unroll 8
            for (int m4 = 0; m4 < M / 4; ++m4) {
                const float4 av = a4[m4];
                const float4 wv = w4[m4];
                acc = fmaf(av.x, wv.x, acc); acc = fmaf(av.y, wv.y, acc);
                acc = fmaf(av.z, wv.z, acc); acc = fmaf(av.w, wv.w, acc);
            }
            sa[h * NN + n] = acc;
        }
        __syncthreads();
        if (t < H) {
            float mx = -1e30f;
#pragma unroll
            for (int n = 0; n < NN; ++n) mx = fmaxf(mx, sa[t * NN + n]);
            float e[NN];
            float s = 0.f;
#pragma unroll
            for (int n = 0; n < NN; ++n) { e[n] = __expf(sa[t * NN + n] - mx); s += e[n]; }
            const float inv = 1.f / s;
#pragma unroll
            for (int n = 0; n < NN; ++n) sa[t * NN + n] = e[n] * inv;
        }
        __syncthreads();
        const float cb = conv_b[0];
        float acc0 = 0.f, acc1 = 0.f;
        for (int h = 0; h < H; ++h) {
            float w0 = 0.f, w1 = 0.f;
#pragma unroll
            for (int n = 0; n < NN; ++n) {
                const float a = sa[h * NN + n];
                const float* fr = f + (size_t)((h * NN + n) << 9);
                w0 = fmaf(a, fr[t], w0);
                w1 = fmaf(a, fr[t + 256], w1);
            }
            acc0 = fmaf(cw[h], w0, acc0);
            acc1 = fmaf(cw[h], w1, acc1);
        }
        out[(k << 9) + t]       = fmaxf(acc0 + cb, 0.f) + Xs[(k << 9) + t];
        out[(k << 9) + t + 256] = fmaxf(acc1 + cb, 0.f) + Xs[(k << 9) + t + 256];
        if (k == 0 && t < NN * 3) out[NN * D + t] = ROIs[t];
    }
}

extern "C" void kernel_launch(void* const* d_in, const int* in_sizes, int n_in,
                              void* d_out, int out_size, void* d_ws, size_t ws_size,
                              hipStream_t stream) {
    const float* Xs     = (const float*)d_in[0];
    const float* ROIs   = (const float*)d_in[1];
    // d_in[2] = adj, unused
    const float* FC     = (const float*)d_in[3];
    const float* W1     = (const float*)d_in[4];
    const float* b1     = (const float*)d_in[5];
    const float* W2     = (const float*)d_in[6];
    const float* b2     = (const float*)d_in[7];
    const float* conv_w = (const float*)d_in[8];
    const float* conv_b = (const float*)d_in[9];
    float* out = (float*)d_out;

    float* f      = (float*)d_ws;              // H*NN*D  = 69632 floats
    float* hdn    = f + H * NN * D;            // H*NN*M  = 34816 floats
    unsigned* sy  = (unsigned*)(hdn + H * NN * M);   // sync counter

    ka <<<128, 256, 0, stream>>>(Xs, FC, f, sy);
    kbc<<<64,  256, 0, stream>>>(Xs, ROIs, W1, b1, W2, b2, conv_w, conv_b,
                                 f, hdn, sy, out);
}